// Round 6
// baseline (228.894 us; speedup 1.0000x reference)
//
#include <hip/hip_runtime.h>

// ---------------------------------------------------------------------------
// Output depends ONLY on positions[0:64]. ~25 MFLOP total.
//
// R6: TWO kernels (stream barrier carries the one real cross-block dep).
//  S1 (8 blocks = row-groups): replicated backbone (winner/h1/h2 for own 8
//     rows), gf rows in LDS (no global round-trip), tpart contribution for
//     ALL 256 j by streaming Wn1 through a 4-slot LDS rotation; every
//     global_load_lds batch is issued one __syncthreads before its consume.
//  S2 (4 blocks = heads): replicated tbar+agg (Wn2 streamed through two
//     64KB LDS halves), then Wh1[k] (128KB) staged, heads + final dot -> out.
// R5 lesson: grid.sync >> kernel boundary cost on MI355X at low occupancy.
//
// BIT-EXACTNESS: harness demands bit-exact bf16 (R1 failed by one ulp).
// All per-output accumulations keep the VERBATIM R4/R5-passing expression
// structure and ascending chunk order; acc registers persist across restage
// boundaries so chunked staging does not reassociate anything.
// ---------------------------------------------------------------------------

__device__ __forceinline__ void async_cp16(const float* g, float* l) {
    __builtin_amdgcn_global_load_lds(
        (const __attribute__((address_space(1))) void*)g,
        (__attribute__((address_space(3))) void*)l, 16, 0, 0);
}
// contiguous: nfloats multiple of 256; 1 inst moves 256 floats (64 lanes x 16B)
__device__ __forceinline__ void stage_contig(const float* g, float* l, int nfloats, int tid) {
    const int lane = tid & 63, wv = tid >> 6;
    const int ninst = nfloats >> 8;
    for (int i = wv; i < ninst; i += 4)
        async_cp16(g + i*256 + lane*4, l + i*256);
}

// ---------------- S1: 8 blocks x 256, dynamic LDS 145408 B ----------------
// layout (floats): w3a[24576] | w2r[8192] | h1[512] | h2[1024] | gf[2048]
#define S1_W3A 0
#define S1_W2R 24576
#define S1_H1  32768
#define S1_H2  33280
#define S1_GF  34304
#define S1_SMEM_BYTES (36352*4)

__global__ __launch_bounds__(256) void s1_grid(
    const float* __restrict__ positions, const float* __restrict__ grid_pts,
    const float* __restrict__ W1, const float* __restrict__ b1,
    const float* __restrict__ W2, const float* __restrict__ b2,
    const float* __restrict__ W3, const float* __restrict__ b3,
    const float* __restrict__ Wn1, const float* __restrict__ bn1,
    float* __restrict__ tpart_ws)      // (8,256)
{
    extern __shared__ float sm[];
    __shared__ float pos_s[192], grid_s[192], w1_s[192], b1_s[64];
    __shared__ int   idx_s[64], win_s[8];

    float* w3a = sm + S1_W3A;   // W3 rows 0..95, later Wn1 chunk slots 0..2
    float* w2r = sm + S1_W2R;   // W2, later W3 rows 96..127, later Wn1 chunk
    float* h1s = sm + S1_H1;
    float* h2s = sm + S1_H2;
    float* gfs = sm + S1_GF;

    const int tid = threadIdx.x;
    const int bg  = blockIdx.x;        // row-group: global rows bg*8 .. bg*8+7

    // entry: stage W2 (32K) + W3 rows0..95 (96K); small arrays plain
    stage_contig(W2, w2r, 8192, tid);
    stage_contig(W3, w3a, 24576, tid);
    if (tid < 192) { pos_s[tid] = positions[tid]; grid_s[tid] = grid_pts[tid]; w1_s[tid] = W1[tid]; }
    if (tid >= 192) b1_s[tid - 192] = b1[tid - 192];
    const float bb2  = b2[tid & 127];
    const float bb3  = b3[tid];
    const float bbn1 = bn1[tid];
    __syncthreads();                                        // A

    if (tid < 64) {                      // verbatim argmin
        const float px = pos_s[tid*3], py = pos_s[tid*3+1], pz = pos_s[tid*3+2];
        float best = 3.4e38f; int bi = 0;
        for (int g = 0; g < 64; ++g) {
            const float dx = px - grid_s[g*3];
            const float dy = py - grid_s[g*3+1];
            const float dz = pz - grid_s[g*3+2];
            const float d2 = dx*dx + dy*dy + dz*dz;
            if (d2 < best) { best = d2; bi = g; }
        }
        idx_s[tid] = bi;
    }
    __syncthreads();                                        // B
    if (tid < 8) {                       // verbatim winner rule, my 8 rows
        const int g = bg*8 + tid;
        int m = -1;
        for (int i = 0; i < 64; ++i) if (idx_s[i] == g) m = i;
        win_s[tid] = m;
    }
    __syncthreads();                                        // C

    // h1 for my 8 rows (512 outputs): verbatim expression
    #pragma unroll
    for (int u = 0; u < 2; ++u) {
        const int e  = tid + u*256;
        const int lr = e >> 6, k = e & 63;
        int r = win_s[lr]; if (r < 0) r = 0;
        const float acc = b1_s[k] + pos_s[r*3]*w1_s[k] + pos_s[r*3+1]*w1_s[64+k]
                                  + pos_s[r*3+2]*w1_s[128+k];
        h1s[lr*64 + k] = fmaxf(acc, 0.f);
    }
    __syncthreads();                                        // D

    // h2 for my 8 rows: verbatim R4-k0 stage with bp == bg
    {
        const int d = tid & 127, t0 = tid >> 7;
        float acc[4];
        #pragma unroll
        for (int m = 0; m < 4; ++m) acc[m] = bb2;
        for (int kc = 0; kc < 64; kc += 16) {
            float w[16];
            #pragma unroll
            for (int u = 0; u < 16; ++u) w[u] = w2r[(kc+u)*128 + d];
            #pragma unroll
            for (int u = 0; u < 16; u += 4) {
                #pragma unroll
                for (int m = 0; m < 4; ++m) {
                    const float4 h4 = *(const float4*)&h1s[(t0 + 2*m)*64 + kc + u];
                    acc[m] += h4.x*w[u] + h4.y*w[u+1] + h4.z*w[u+2] + h4.w*w[u+3];
                }
            }
        }
        #pragma unroll
        for (int m = 0; m < 4; ++m)
            h2s[(t0 + 2*m)*128 + d] = fmaxf(acc[m], 0.f);
    }
    __syncthreads();                                        // E (w2r free)
    stage_contig(W3 + 96*256, w2r, 8192, tid);              // W3 rows 96..127

    // gf: verbatim R4-k1 accumulation, thread = col j, rows = my 8
    const int j = tid;
    float ag[8];
    #pragma unroll
    for (int t = 0; t < 8; ++t) ag[t] = 0.f;
    for (int dc = 0; dc < 96; dc += 16) {                   // part 1 (w3a)
        float w[16];
        #pragma unroll
        for (int u = 0; u < 16; ++u) w[u] = w3a[(dc+u)*256 + j];
        #pragma unroll
        for (int u = 0; u < 16; u += 4) {
            #pragma unroll
            for (int t = 0; t < 8; ++t) {
                const float4 h4 = *(const float4*)&h2s[t*128 + dc + u];
                ag[t] += h4.x*w[u] + h4.y*w[u+1] + h4.z*w[u+2] + h4.w*w[u+3];
            }
        }
    }
    __syncthreads();                                        // F (w3a free; W3b landed)
    stage_contig(Wn1,            w3a,         8192, tid);   // chunk0 -> slot0
    stage_contig(Wn1 + 1*8192,   w3a + 8192,  8192, tid);   // chunk1 -> slot1
    stage_contig(Wn1 + 2*8192,   w3a + 16384, 8192, tid);   // chunk2 -> slot2
    for (int dc = 96; dc < 128; dc += 16) {                 // part 2 (w2r)
        float w[16];
        #pragma unroll
        for (int u = 0; u < 16; ++u) w[u] = w2r[(dc-96+u)*256 + j];
        #pragma unroll
        for (int u = 0; u < 16; u += 4) {
            #pragma unroll
            for (int t = 0; t < 8; ++t) {
                const float4 h4 = *(const float4*)&h2s[t*128 + dc + u];
                ag[t] += h4.x*w[u] + h4.y*w[u+1] + h4.z*w[u+2] + h4.w*w[u+3];
            }
        }
    }
    #pragma unroll
    for (int t = 0; t < 8; ++t)
        gfs[t*256 + j] = (win_s[t] >= 0) ? (ag[t] + bb3) : 0.f;
    __syncthreads();                                        // G (chunks0-2 landed; w2r free)
    stage_contig(Wn1 + 3*8192, w2r, 8192, tid);             // chunk3

    // tpart: verbatim accumulation, cc ascending 0..224 step 32
    float ac[8];
    #pragma unroll
    for (int t = 0; t < 8; ++t) ac[t] = bbn1;
    #pragma unroll
    for (int ch = 0; ch < 3; ++ch) {                        // cc = 0,32,64
        const int cc = ch*32;
        float w[32];
        #pragma unroll
        for (int u = 0; u < 32; ++u) w[u] = w3a[ch*8192 + u*256 + j];
        #pragma unroll
        for (int u = 0; u < 32; u += 4) {
            #pragma unroll
            for (int t = 0; t < 8; ++t) {
                const float4 g4 = *(const float4*)&gfs[t*256 + cc + u];
                ac[t] += g4.x*w[u] + g4.y*w[u+1] + g4.z*w[u+2] + g4.w*w[u+3];
            }
        }
    }
    __syncthreads();                                        // H (chunk3 landed; w3a free)
    stage_contig(Wn1 + 4*8192, w3a,         8192, tid);
    stage_contig(Wn1 + 5*8192, w3a + 8192,  8192, tid);
    stage_contig(Wn1 + 6*8192, w3a + 16384, 8192, tid);
    {                                                       // cc = 96 (w2r)
        const int cc = 96;
        float w[32];
        #pragma unroll
        for (int u = 0; u < 32; ++u) w[u] = w2r[u*256 + j];
        #pragma unroll
        for (int u = 0; u < 32; u += 4) {
            #pragma unroll
            for (int t = 0; t < 8; ++t) {
                const float4 g4 = *(const float4*)&gfs[t*256 + cc + u];
                ac[t] += g4.x*w[u] + g4.y*w[u+1] + g4.z*w[u+2] + g4.w*w[u+3];
            }
        }
    }
    __syncthreads();                                        // I (chunks4-6 landed; w2r free)
    stage_contig(Wn1 + 7*8192, w2r, 8192, tid);             // chunk7
    #pragma unroll
    for (int ch = 0; ch < 3; ++ch) {                        // cc = 128,160,192
        const int cc = 128 + ch*32;
        float w[32];
        #pragma unroll
        for (int u = 0; u < 32; ++u) w[u] = w3a[ch*8192 + u*256 + j];
        #pragma unroll
        for (int u = 0; u < 32; u += 4) {
            #pragma unroll
            for (int t = 0; t < 8; ++t) {
                const float4 g4 = *(const float4*)&gfs[t*256 + cc + u];
                ac[t] += g4.x*w[u] + g4.y*w[u+1] + g4.z*w[u+2] + g4.w*w[u+3];
            }
        }
    }
    __syncthreads();                                        // J (chunk7 landed)
    {                                                       // cc = 224 (w2r)
        const int cc = 224;
        float w[32];
        #pragma unroll
        for (int u = 0; u < 32; ++u) w[u] = w2r[u*256 + j];
        #pragma unroll
        for (int u = 0; u < 32; u += 4) {
            #pragma unroll
            for (int t = 0; t < 8; ++t) {
                const float4 g4 = *(const float4*)&gfs[t*256 + cc + u];
                ac[t] += g4.x*w[u] + g4.y*w[u+1] + g4.z*w[u+2] + g4.w*w[u+3];
            }
        }
    }
    // ps: relu'd rows summed ascending (verbatim two-level order, level 1)
    float ps = 0.f;
    #pragma unroll
    for (int t = 0; t < 8; ++t) ps += fmaxf(ac[t], 0.f);
    tpart_ws[bg*256 + j] = ps;
}

// ---------------- S2: 4 blocks x 256, dynamic LDS 131072 B ----------------
#define S2_SMEM_BYTES (32768*4)

__global__ __launch_bounds__(256) void s2_head(
    const float* __restrict__ Wn2, const float* __restrict__ bn2,
    const float* __restrict__ Wh1, const float* __restrict__ bh1,
    const float* __restrict__ Wh2, const float* __restrict__ bh2,
    const float* __restrict__ tpart_ws,                     // (8,256)
    float* __restrict__ out)                                // (4)
{
    extern __shared__ float sm[];
    __shared__ __align__(16) float tp_s[2048];
    __shared__ __align__(16) float tbar_s[256];
    __shared__ __align__(16) float agg_s[256];
    __shared__ __align__(16) float h1h_s[128];
    __shared__ __align__(16) float wh2_s[128];

    float* bufA = sm;            // 16384 floats (64 KB)
    float* bufB = sm + 16384;    // 16384 floats

    const int tid = threadIdx.x;
    const int k   = blockIdx.x;

    stage_contig(tpart_ws, tp_s, 2048, tid);
    stage_contig(Wn2,          bufA, 16384, tid);           // rows 0..63
    stage_contig(Wn2 + 16384,  bufB, 16384, tid);           // rows 64..127
    const float bbn2  = bn2[tid];
    const float bbh1k = (tid < 128) ? bh1[k*128 + tid] : 0.f;
    if (tid < 128) wh2_s[tid] = Wh2[k*128 + tid];
    const float bbh2k = bh2[k];
    __syncthreads();                                        // A

    {   // tbar: verbatim (q ascending, then *1/64)
        float tb = 0.f;
        #pragma unroll
        for (int q = 0; q < 8; ++q) tb += tp_s[q*256 + tid];
        tbar_s[tid] = tb * (1.f/64.f);
    }
    __syncthreads();                                        // B

    // agg: verbatim chunk structure, jc ascending 0..255, thread c = tid
    float acc = bbn2;
    for (int jc = 0; jc < 64; jc += 32) {                   // bufA
        float w[32];
        #pragma unroll
        for (int u = 0; u < 32; ++u) w[u] = bufA[(jc+u)*256 + tid];
        #pragma unroll
        for (int u = 0; u < 32; u += 4) {
            const float4 t4 = *(const float4*)&tbar_s[jc + u];
            acc += t4.x*w[u] + t4.y*w[u+1] + t4.z*w[u+2] + t4.w*w[u+3];
        }
    }
    __syncthreads();                                        // C (bufA free)
    stage_contig(Wn2 + 32768, bufA, 16384, tid);            // rows 128..191
    for (int jc = 64; jc < 128; jc += 32) {                 // bufB
        float w[32];
        #pragma unroll
        for (int u = 0; u < 32; ++u) w[u] = bufB[(jc-64+u)*256 + tid];
        #pragma unroll
        for (int u = 0; u < 32; u += 4) {
            const float4 t4 = *(const float4*)&tbar_s[jc + u];
            acc += t4.x*w[u] + t4.y*w[u+1] + t4.z*w[u+2] + t4.w*w[u+3];
        }
    }
    __syncthreads();                                        // D (bufB free)
    stage_contig(Wn2 + 49152, bufB, 16384, tid);            // rows 192..255
    for (int jc = 128; jc < 192; jc += 32) {                // bufA
        float w[32];
        #pragma unroll
        for (int u = 0; u < 32; ++u) w[u] = bufA[(jc-128+u)*256 + tid];
        #pragma unroll
        for (int u = 0; u < 32; u += 4) {
            const float4 t4 = *(const float4*)&tbar_s[jc + u];
            acc += t4.x*w[u] + t4.y*w[u+1] + t4.z*w[u+2] + t4.w*w[u+3];
        }
    }
    __syncthreads();                                        // E
    for (int jc = 192; jc < 256; jc += 32) {                // bufB
        float w[32];
        #pragma unroll
        for (int u = 0; u < 32; ++u) w[u] = bufB[(jc-192+u)*256 + tid];
        #pragma unroll
        for (int u = 0; u < 32; u += 4) {
            const float4 t4 = *(const float4*)&tbar_s[jc + u];
            acc += t4.x*w[u] + t4.y*w[u+1] + t4.z*w[u+2] + t4.w*w[u+3];
        }
    }
    agg_s[tid] = acc;
    __syncthreads();                                        // F (bufs free)
    stage_contig(Wh1 + k*32768,         bufA, 16384, tid);  // Wh1[k] rows 0..127
    stage_contig(Wh1 + k*32768 + 16384, bufB, 16384, tid);  // rows 128..255
    __syncthreads();                                        // G

    if (tid < 128) {   // heads: verbatim chunk structure, cc ascending
        const int d = tid;
        float a = bbh1k;
        for (int cc = 0; cc < 128; cc += 16) {
            float wa[16];
            #pragma unroll
            for (int u = 0; u < 16; ++u) wa[u] = bufA[(cc+u)*128 + d];
            #pragma unroll
            for (int u = 0; u < 16; u += 4) {
                const float4 a4 = *(const float4*)&agg_s[cc + u];
                a += a4.x*wa[u] + a4.y*wa[u+1] + a4.z*wa[u+2] + a4.w*wa[u+3];
            }
        }
        for (int cc = 128; cc < 256; cc += 16) {
            float wa[16];
            #pragma unroll
            for (int u = 0; u < 16; ++u) wa[u] = bufB[(cc-128+u)*128 + d];
            #pragma unroll
            for (int u = 0; u < 16; u += 4) {
                const float4 a4 = *(const float4*)&agg_s[cc + u];
                a += a4.x*wa[u] + a4.y*wa[u+1] + a4.z*wa[u+2] + a4.w*wa[u+3];
            }
        }
        h1h_s[d] = fmaxf(a, 0.f);
    }
    __syncthreads();                                        // H
    if (tid == 0) {    // verbatim strictly-sequential final dot
        float a = bbh2k;
        for (int d = 0; d < 128; ++d) a += h1h_s[d] * wh2_s[d];
        out[k] = a;
    }
}

extern "C" void kernel_launch(void* const* d_in, const int* in_sizes, int n_in,
                              void* d_out, int out_size, void* d_ws, size_t ws_size,
                              hipStream_t stream) {
    const float* positions = (const float*)d_in[0];
    const float* grid      = (const float*)d_in[1];
    const float* W1  = (const float*)d_in[2];
    const float* b1  = (const float*)d_in[3];
    const float* W2  = (const float*)d_in[4];
    const float* b2  = (const float*)d_in[5];
    const float* W3  = (const float*)d_in[6];
    const float* b3  = (const float*)d_in[7];
    const float* Wn1 = (const float*)d_in[8];
    const float* bn1 = (const float*)d_in[9];
    const float* Wn2 = (const float*)d_in[10];
    const float* bn2 = (const float*)d_in[11];
    const float* Wh1 = (const float*)d_in[12];
    const float* bh1 = (const float*)d_in[13];
    const float* Wh2 = (const float*)d_in[14];
    const float* bh2 = (const float*)d_in[15];
    float* out = (float*)d_out;

    float* tpart_ws = (float*)d_ws;   // 8*256 f32, fully rewritten every call

    // allow >64K dynamic LDS (host-side attr, capture-safe; proven in R5)
    (void)hipFuncSetAttribute((const void*)s1_grid,
                              hipFuncAttributeMaxDynamicSharedMemorySize,
                              S1_SMEM_BYTES);
    (void)hipFuncSetAttribute((const void*)s2_head,
                              hipFuncAttributeMaxDynamicSharedMemorySize,
                              S2_SMEM_BYTES);

    hipLaunchKernelGGL(s1_grid, dim3(8), dim3(256), S1_SMEM_BYTES, stream,
                       positions, grid, W1, b1, W2, b2, W3, b3, Wn1, bn1,
                       tpart_ws);
    hipLaunchKernelGGL(s2_head, dim3(4), dim3(256), S2_SMEM_BYTES, stream,
                       Wn2, bn2, Wh1, bh1, Wh2, bh2, tpart_ws, out);
}

// Round 7
// 111.516 us; speedup vs baseline: 2.0526x; 2.0526x over previous
//
#include <hip/hip_runtime.h>

// ---------------------------------------------------------------------------
// Output depends ONLY on positions[0:64]. ~25 MFLOP total.
//
// R7: 4 kernels, R4's proven low-VGPR shape (stage-at-entry, ONE drain, w[16]
// chunks, no LDS rotation -- R6's rotation spilled to 256 VGPR / 6.4MB scratch
// and ran 175us).
//  A (8 blocks = row-groups): replicated backbone (winner/h1/h2 for own 8
//     rows; W2 via chunked global = R2-proven), gf for own 8 rows vs FULL W3
//     staged at entry (128 KB LDS) -> gf_ws.      [merges R4 k0+k1]
//  B (64 blocks): R4 k2 verbatim -> tpart_ws.
//  C (8 blocks):  R4 k3 verbatim -> agg_ws.
//  D (4 blocks = heads): Wh1[k] (128 KB) staged at entry, h1h (R5-proven
//     full-width expression), verbatim scalar final dot -> out. [merges k4+k5]
//
// BIT-EXACTNESS: harness demands bit-exact bf16 (R1 failed by one ulp).
// Every per-output accumulation keeps the VERBATIM expression structure and
// ascending chunk order from rounds that scored absmax 0.0. Do not
// reassociate; do not regroup.
// ---------------------------------------------------------------------------

__device__ __forceinline__ void async_cp16(const float* g, float* l) {
    __builtin_amdgcn_global_load_lds(
        (const __attribute__((address_space(1))) void*)g,
        (__attribute__((address_space(3))) void*)l, 16, 0, 0);
}
// contiguous: nfloats multiple of 256; 1 inst moves 256 floats (64 lanes x 16B)
__device__ __forceinline__ void stage_contig(const float* g, float* l, int nfloats, int tid) {
    const int lane = tid & 63, wv = tid >> 6;
    const int ninst = nfloats >> 8;
    for (int i = wv; i < ninst; i += 4)
        async_cp16(g + i*256 + lane*4, l + i*256);
}
// 32-col slice of row-major [nrows][ld] at col j0 -> LDS [r][32]
__device__ __forceinline__ void stage_slice32(const float* g, float* l, int ld, int j0, int nrows, int tid) {
    const int lane = tid & 63, wv = tid >> 6;
    const int r = lane >> 3, c4 = (lane & 7) << 2;
    const int ninst = nrows >> 3;
    for (int i = wv; i < ninst; i += 4)
        async_cp16(g + (i*8 + r)*ld + j0 + c4, l + i*256);
}

// ---- A (8 blocks): replicated backbone + gf for own 8 rows ----------------
#define A_SMEM_BYTES (32768*4)   // full W3 in dynamic LDS

__global__ __launch_bounds__(256) void a_gf(
    const float* __restrict__ positions, const float* __restrict__ grid_pts,
    const float* __restrict__ W1, const float* __restrict__ b1,
    const float* __restrict__ W2, const float* __restrict__ b2,
    const float* __restrict__ W3, const float* __restrict__ b3,
    float* __restrict__ gf_ws)                              // (64,256)
{
    extern __shared__ float w3s[];                          // 128 KB: W3 full
    __shared__ float pos_s[192], grid_s[192], w1_s[192], b1_s[64];
    __shared__ int   idx_s[64], win_s[8];
    __shared__ __align__(16) float h1s[8*64];
    __shared__ __align__(16) float h2s[8*128];

    const int tid = threadIdx.x;
    const int bg  = blockIdx.x;        // rows bg*8 .. bg*8+7

    stage_contig(W3, w3s, 32768, tid);                      // async at entry
    if (tid < 192) { pos_s[tid] = positions[tid]; grid_s[tid] = grid_pts[tid]; w1_s[tid] = W1[tid]; }
    if (tid >= 192) b1_s[tid - 192] = b1[tid - 192];
    const float bb2 = b2[tid & 127];
    const float bb3 = b3[tid];
    __syncthreads();                                        // ONE drain

    if (tid < 64) {                      // verbatim argmin
        const float px = pos_s[tid*3], py = pos_s[tid*3+1], pz = pos_s[tid*3+2];
        float best = 3.4e38f; int bi = 0;
        for (int g = 0; g < 64; ++g) {
            const float dx = px - grid_s[g*3];
            const float dy = py - grid_s[g*3+1];
            const float dz = pz - grid_s[g*3+2];
            const float d2 = dx*dx + dy*dy + dz*dz;
            if (d2 < best) { best = d2; bi = g; }
        }
        idx_s[tid] = bi;
    }
    __syncthreads();
    if (tid < 8) {                       // verbatim winner rule, own 8 rows
        const int g = bg*8 + tid;
        int m = -1;
        for (int i = 0; i < 64; ++i) if (idx_s[i] == g) m = i;
        win_s[tid] = m;
    }
    __syncthreads();

    // h1 own 8 rows (512 outs): verbatim expression (R6 backbone, passed)
    #pragma unroll
    for (int u = 0; u < 2; ++u) {
        const int e  = tid + u*256;
        const int lr = e >> 6, k = e & 63;
        int r = win_s[lr]; if (r < 0) r = 0;
        const float acc = b1_s[k] + pos_s[r*3]*w1_s[k] + pos_s[r*3+1]*w1_s[64+k]
                                  + pos_s[r*3+2]*w1_s[128+k];
        h1s[lr*64 + k] = fmaxf(acc, 0.f);
    }
    __syncthreads();

    // h2 own 8 rows: verbatim chunk structure; W2 via chunked GLOBAL loads
    // (R2-kA-proven expression; only 4 latency rounds, overlapped w/ nothing
    // critical -- W3 already resident)
    {
        const int d = tid & 127, t0 = tid >> 7;
        float acc[4];
        #pragma unroll
        for (int m = 0; m < 4; ++m) acc[m] = bb2;
        for (int kc = 0; kc < 64; kc += 16) {
            float w[16];
            #pragma unroll
            for (int u = 0; u < 16; ++u) w[u] = W2[(kc+u)*128 + d];
            #pragma unroll
            for (int u = 0; u < 16; u += 4) {
                #pragma unroll
                for (int m = 0; m < 4; ++m) {
                    const float4 h4 = *(const float4*)&h1s[(t0 + 2*m)*64 + kc + u];
                    acc[m] += h4.x*w[u] + h4.y*w[u+1] + h4.z*w[u+2] + h4.w*w[u+3];
                }
            }
        }
        #pragma unroll
        for (int m = 0; m < 4; ++m)
            h2s[(t0 + 2*m)*128 + d] = fmaxf(acc[m], 0.f);
    }
    __syncthreads();

    // gf own 8 rows x all 256 cols: verbatim R4-k1 accumulation, W3 from LDS
    {
        const int j = tid;
        float ag[8];
        #pragma unroll
        for (int t = 0; t < 8; ++t) ag[t] = 0.f;
        for (int dc = 0; dc < 128; dc += 16) {
            float w[16];
            #pragma unroll
            for (int u = 0; u < 16; ++u) w[u] = w3s[(dc+u)*256 + j];
            #pragma unroll
            for (int u = 0; u < 16; u += 4) {
                #pragma unroll
                for (int t = 0; t < 8; ++t) {
                    const float4 h4 = *(const float4*)&h2s[t*128 + dc + u];
                    ag[t] += h4.x*w[u] + h4.y*w[u+1] + h4.z*w[u+2] + h4.w*w[u+3];
                }
            }
        }
        #pragma unroll
        for (int t = 0; t < 8; ++t)
            gf_ws[(bg*8 + t)*256 + j] = (win_s[t] >= 0) ? (ag[t] + bb3) : 0.f;
    }
}

// ---- B (64 blocks): R4 k2 verbatim -> tpart ------------------------------
__global__ __launch_bounds__(256) void k2_tpart(
    const float* __restrict__ Wn1, const float* __restrict__ bn1,
    const float* __restrict__ gf_ws, float* __restrict__ tpart_ws)
{
    __shared__ __align__(16) float wn1_s[256*32];
    __shared__ __align__(16) float gf_s[8*256];
    __shared__ float r_s[256];

    const int tid = threadIdx.x;
    const int bg  = blockIdx.x >> 3;
    const int j0  = (blockIdx.x & 7) * 32;
    stage_slice32(Wn1, wn1_s, 256, j0, 256, tid);
    stage_contig(gf_ws + bg*8*256, gf_s, 8*256, tid);

    const int jl = tid & 31, t = tid >> 5;
    const float bb = bn1[j0 + jl];
    __syncthreads();

    float acc = bb;
    for (int cc = 0; cc < 256; cc += 32) {
        float w[32];
        #pragma unroll
        for (int u = 0; u < 32; ++u) w[u] = wn1_s[(cc+u)*32 + jl];
        #pragma unroll
        for (int u = 0; u < 32; u += 4) {
            const float4 g4 = *(const float4*)&gf_s[t*256 + cc + u];
            acc += g4.x*w[u] + g4.y*w[u+1] + g4.z*w[u+2] + g4.w*w[u+3];
        }
    }
    r_s[tid] = fmaxf(acc, 0.f);
    __syncthreads();
    if (t == 0) {
        float ps = 0.f;
        #pragma unroll
        for (int tt = 0; tt < 8; ++tt) ps += r_s[tt*32 + jl];
        tpart_ws[bg*256 + j0 + jl] = ps;
    }
}

// ---- C (8 blocks): R4 k3 verbatim -> agg ---------------------------------
__global__ __launch_bounds__(256) void k3_agg(
    const float* __restrict__ Wn2, const float* __restrict__ bn2,
    const float* __restrict__ tpart_ws, float* __restrict__ agg_ws)
{
    __shared__ __align__(16) float wn2_s[256*32];
    __shared__ __align__(16) float tp_s[8*256];
    __shared__ __align__(16) float tbars[256];

    const int tid = threadIdx.x;
    const int c0  = blockIdx.x * 32;
    stage_slice32(Wn2, wn2_s, 256, c0, 256, tid);
    stage_contig(tpart_ws, tp_s, 8*256, tid);

    const float bb = (tid < 32) ? bn2[c0 + tid] : 0.f;
    __syncthreads();

    {
        float tb = 0.f;
        #pragma unroll
        for (int q = 0; q < 8; ++q) tb += tp_s[q*256 + tid];
        tbars[tid] = tb * (1.f/64.f);
    }
    __syncthreads();

    if (tid < 32) {
        float acc = bb;
        for (int jc = 0; jc < 256; jc += 32) {
            float w[32];
            #pragma unroll
            for (int u = 0; u < 32; ++u) w[u] = wn2_s[(jc+u)*32 + tid];
            #pragma unroll
            for (int u = 0; u < 32; u += 4) {
                const float4 t4 = *(const float4*)&tbars[jc + u];
                acc += t4.x*w[u] + t4.y*w[u+1] + t4.z*w[u+2] + t4.w*w[u+3];
            }
        }
        agg_ws[c0 + tid] = acc;
    }
}

// ---- D (4 blocks = heads): h1h + final dot -> out ------------------------
#define D_SMEM_BYTES (32768*4)   // Wh1[k] in dynamic LDS

__global__ __launch_bounds__(256) void d_heads(
    const float* __restrict__ Wh1, const float* __restrict__ bh1,
    const float* __restrict__ Wh2, const float* __restrict__ bh2,
    const float* __restrict__ agg_ws, float* __restrict__ out)
{
    extern __shared__ float wh1s[];                         // 128 KB: Wh1[k]
    __shared__ __align__(16) float agg_s[256];
    __shared__ __align__(16) float h1h_s[128];
    __shared__ __align__(16) float wh2_s[128];

    const int tid = threadIdx.x;
    const int k   = blockIdx.x;

    stage_contig(Wh1 + k*32768, wh1s, 32768, tid);          // async at entry
    stage_contig(agg_ws, agg_s, 256, tid);                  // async
    const float bbh1 = (tid < 128) ? bh1[k*128 + tid] : 0.f;
    if (tid < 128) wh2_s[tid] = Wh2[k*128 + tid];
    const float bbh2 = bh2[k];
    __syncthreads();                                        // ONE drain

    if (tid < 128) {   // verbatim R5-phase-4 head expression (passed)
        const int d = tid;
        float acc = bbh1;
        for (int cc = 0; cc < 256; cc += 16) {
            float wa[16];
            #pragma unroll
            for (int u = 0; u < 16; ++u) wa[u] = wh1s[(cc+u)*128 + d];
            #pragma unroll
            for (int u = 0; u < 16; u += 4) {
                const float4 a4 = *(const float4*)&agg_s[cc + u];
                acc += a4.x*wa[u] + a4.y*wa[u+1] + a4.z*wa[u+2] + a4.w*wa[u+3];
            }
        }
        h1h_s[d] = fmaxf(acc, 0.f);
    }
    __syncthreads();
    if (tid == 0) {    // verbatim strictly-sequential final dot
        float acc = bbh2;
        for (int d = 0; d < 128; ++d) acc += h1h_s[d] * wh2_s[d];
        out[k] = acc;
    }
}

extern "C" void kernel_launch(void* const* d_in, const int* in_sizes, int n_in,
                              void* d_out, int out_size, void* d_ws, size_t ws_size,
                              hipStream_t stream) {
    const float* positions = (const float*)d_in[0];
    const float* grid      = (const float*)d_in[1];
    const float* W1  = (const float*)d_in[2];
    const float* b1  = (const float*)d_in[3];
    const float* W2  = (const float*)d_in[4];
    const float* b2  = (const float*)d_in[5];
    const float* W3  = (const float*)d_in[6];
    const float* b3  = (const float*)d_in[7];
    const float* Wn1 = (const float*)d_in[8];
    const float* bn1 = (const float*)d_in[9];
    const float* Wn2 = (const float*)d_in[10];
    const float* bn2 = (const float*)d_in[11];
    const float* Wh1 = (const float*)d_in[12];
    const float* bh1 = (const float*)d_in[13];
    const float* Wh2 = (const float*)d_in[14];
    const float* bh2 = (const float*)d_in[15];
    float* out = (float*)d_out;

    char* ws = (char*)d_ws;                 // fully rewritten every call
    float* gf_ws    = (float*)(ws + 0);         // 64*256 f = 64 KB
    float* tpart_ws = (float*)(ws + 65536);     // 8*256 f = 8 KB
    float* agg_ws   = (float*)(ws + 73728);     // 256 f

    (void)hipFuncSetAttribute((const void*)a_gf,
                              hipFuncAttributeMaxDynamicSharedMemorySize,
                              A_SMEM_BYTES);
    (void)hipFuncSetAttribute((const void*)d_heads,
                              hipFuncAttributeMaxDynamicSharedMemorySize,
                              D_SMEM_BYTES);

    hipLaunchKernelGGL(a_gf,     dim3(8),  dim3(256), A_SMEM_BYTES, stream,
                       positions, grid, W1, b1, W2, b2, W3, b3, gf_ws);
    hipLaunchKernelGGL(k2_tpart, dim3(64), dim3(256), 0, stream,
                       Wn1, bn1, gf_ws, tpart_ws);
    hipLaunchKernelGGL(k3_agg,   dim3(8),  dim3(256), 0, stream,
                       Wn2, bn2, tpart_ws, agg_ws);
    hipLaunchKernelGGL(d_heads,  dim3(4),  dim3(256), D_SMEM_BYTES, stream,
                       Wh1, bh1, Wh2, bh2, agg_ws, out);
}

// Round 8
// 110.143 us; speedup vs baseline: 2.0782x; 1.0125x over previous
//
#include <hip/hip_runtime.h>

// ---------------------------------------------------------------------------
// Output depends ONLY on positions[0:64]. ~25 MFLOP total.
//
// R8: 3 kernels (slot cut 4->3 by merging agg+heads into the R6-proven
// s2_head, which was bit-exact; R6's regression was s1's spills only).
//  A (8 blocks = row-groups): replicated backbone + gf vs full W3 in LDS
//     -> gf_ws.                                   [R7 a_gf, verbatim]
//  B (64 blocks): Wn1-slice tpart                 [R7 k2_tpart, verbatim]
//  CD (4 blocks = heads): replicated tbar+agg (Wn2 streamed through two
//     64KB LDS halves) + Wh1[k] heads + final dot [R6 s2_head, verbatim]
//
// BIT-EXACTNESS: harness demands bit-exact bf16 (R1 failed by one ulp).
// Every per-output accumulation keeps the VERBATIM expression structure and
// ascending chunk order from rounds that scored absmax 0.0. Do not
// reassociate; do not regroup. Keep register profiles flat (R6 lesson:
// LDS rotation + chained unrolled chunks -> 256 VGPR spill disaster).
// ---------------------------------------------------------------------------

__device__ __forceinline__ void async_cp16(const float* g, float* l) {
    __builtin_amdgcn_global_load_lds(
        (const __attribute__((address_space(1))) void*)g,
        (__attribute__((address_space(3))) void*)l, 16, 0, 0);
}
// contiguous: nfloats multiple of 256; 1 inst moves 256 floats (64 lanes x 16B)
__device__ __forceinline__ void stage_contig(const float* g, float* l, int nfloats, int tid) {
    const int lane = tid & 63, wv = tid >> 6;
    const int ninst = nfloats >> 8;
    for (int i = wv; i < ninst; i += 4)
        async_cp16(g + i*256 + lane*4, l + i*256);
}
// 32-col slice of row-major [nrows][ld] at col j0 -> LDS [r][32]
__device__ __forceinline__ void stage_slice32(const float* g, float* l, int ld, int j0, int nrows, int tid) {
    const int lane = tid & 63, wv = tid >> 6;
    const int r = lane >> 3, c4 = (lane & 7) << 2;
    const int ninst = nrows >> 3;
    for (int i = wv; i < ninst; i += 4)
        async_cp16(g + (i*8 + r)*ld + j0 + c4, l + i*256);
}

// ---- A (8 blocks): replicated backbone + gf for own 8 rows ----------------
#define A_SMEM_BYTES (32768*4)   // full W3 in dynamic LDS

__global__ __launch_bounds__(256) void a_gf(
    const float* __restrict__ positions, const float* __restrict__ grid_pts,
    const float* __restrict__ W1, const float* __restrict__ b1,
    const float* __restrict__ W2, const float* __restrict__ b2,
    const float* __restrict__ W3, const float* __restrict__ b3,
    float* __restrict__ gf_ws)                              // (64,256)
{
    extern __shared__ float w3s[];                          // 128 KB: W3 full
    __shared__ float pos_s[192], grid_s[192], w1_s[192], b1_s[64];
    __shared__ int   idx_s[64], win_s[8];
    __shared__ __align__(16) float h1s[8*64];
    __shared__ __align__(16) float h2s[8*128];

    const int tid = threadIdx.x;
    const int bg  = blockIdx.x;        // rows bg*8 .. bg*8+7

    stage_contig(W3, w3s, 32768, tid);                      // async at entry
    if (tid < 192) { pos_s[tid] = positions[tid]; grid_s[tid] = grid_pts[tid]; w1_s[tid] = W1[tid]; }
    if (tid >= 192) b1_s[tid - 192] = b1[tid - 192];
    const float bb2 = b2[tid & 127];
    const float bb3 = b3[tid];
    __syncthreads();                                        // ONE drain

    if (tid < 64) {                      // verbatim argmin
        const float px = pos_s[tid*3], py = pos_s[tid*3+1], pz = pos_s[tid*3+2];
        float best = 3.4e38f; int bi = 0;
        for (int g = 0; g < 64; ++g) {
            const float dx = px - grid_s[g*3];
            const float dy = py - grid_s[g*3+1];
            const float dz = pz - grid_s[g*3+2];
            const float d2 = dx*dx + dy*dy + dz*dz;
            if (d2 < best) { best = d2; bi = g; }
        }
        idx_s[tid] = bi;
    }
    __syncthreads();
    if (tid < 8) {                       // verbatim winner rule, own 8 rows
        const int g = bg*8 + tid;
        int m = -1;
        for (int i = 0; i < 64; ++i) if (idx_s[i] == g) m = i;
        win_s[tid] = m;
    }
    __syncthreads();

    // h1 own 8 rows (512 outs): verbatim expression
    #pragma unroll
    for (int u = 0; u < 2; ++u) {
        const int e  = tid + u*256;
        const int lr = e >> 6, k = e & 63;
        int r = win_s[lr]; if (r < 0) r = 0;
        const float acc = b1_s[k] + pos_s[r*3]*w1_s[k] + pos_s[r*3+1]*w1_s[64+k]
                                  + pos_s[r*3+2]*w1_s[128+k];
        h1s[lr*64 + k] = fmaxf(acc, 0.f);
    }
    __syncthreads();

    // h2 own 8 rows: verbatim chunk structure; W2 via chunked GLOBAL loads
    {
        const int d = tid & 127, t0 = tid >> 7;
        float acc[4];
        #pragma unroll
        for (int m = 0; m < 4; ++m) acc[m] = bb2;
        for (int kc = 0; kc < 64; kc += 16) {
            float w[16];
            #pragma unroll
            for (int u = 0; u < 16; ++u) w[u] = W2[(kc+u)*128 + d];
            #pragma unroll
            for (int u = 0; u < 16; u += 4) {
                #pragma unroll
                for (int m = 0; m < 4; ++m) {
                    const float4 h4 = *(const float4*)&h1s[(t0 + 2*m)*64 + kc + u];
                    acc[m] += h4.x*w[u] + h4.y*w[u+1] + h4.z*w[u+2] + h4.w*w[u+3];
                }
            }
        }
        #pragma unroll
        for (int m = 0; m < 4; ++m)
            h2s[(t0 + 2*m)*128 + d] = fmaxf(acc[m], 0.f);
    }
    __syncthreads();

    // gf own 8 rows x all 256 cols: verbatim accumulation, W3 from LDS
    {
        const int j = tid;
        float ag[8];
        #pragma unroll
        for (int t = 0; t < 8; ++t) ag[t] = 0.f;
        for (int dc = 0; dc < 128; dc += 16) {
            float w[16];
            #pragma unroll
            for (int u = 0; u < 16; ++u) w[u] = w3s[(dc+u)*256 + j];
            #pragma unroll
            for (int u = 0; u < 16; u += 4) {
                #pragma unroll
                for (int t = 0; t < 8; ++t) {
                    const float4 h4 = *(const float4*)&h2s[t*128 + dc + u];
                    ag[t] += h4.x*w[u] + h4.y*w[u+1] + h4.z*w[u+2] + h4.w*w[u+3];
                }
            }
        }
        #pragma unroll
        for (int t = 0; t < 8; ++t)
            gf_ws[(bg*8 + t)*256 + j] = (win_s[t] >= 0) ? (ag[t] + bb3) : 0.f;
    }
}

// ---- B (64 blocks): Wn1-slice tpart (R7 verbatim) ------------------------
__global__ __launch_bounds__(256) void k2_tpart(
    const float* __restrict__ Wn1, const float* __restrict__ bn1,
    const float* __restrict__ gf_ws, float* __restrict__ tpart_ws)
{
    __shared__ __align__(16) float wn1_s[256*32];
    __shared__ __align__(16) float gf_s[8*256];
    __shared__ float r_s[256];

    const int tid = threadIdx.x;
    const int bg  = blockIdx.x >> 3;
    const int j0  = (blockIdx.x & 7) * 32;
    stage_slice32(Wn1, wn1_s, 256, j0, 256, tid);
    stage_contig(gf_ws + bg*8*256, gf_s, 8*256, tid);

    const int jl = tid & 31, t = tid >> 5;
    const float bb = bn1[j0 + jl];
    __syncthreads();

    float acc = bb;
    for (int cc = 0; cc < 256; cc += 32) {
        float w[32];
        #pragma unroll
        for (int u = 0; u < 32; ++u) w[u] = wn1_s[(cc+u)*32 + jl];
        #pragma unroll
        for (int u = 0; u < 32; u += 4) {
            const float4 g4 = *(const float4*)&gf_s[t*256 + cc + u];
            acc += g4.x*w[u] + g4.y*w[u+1] + g4.z*w[u+2] + g4.w*w[u+3];
        }
    }
    r_s[tid] = fmaxf(acc, 0.f);
    __syncthreads();
    if (t == 0) {
        float ps = 0.f;
        #pragma unroll
        for (int tt = 0; tt < 8; ++tt) ps += r_s[tt*32 + jl];
        tpart_ws[bg*256 + j0 + jl] = ps;
    }
}

// ---- CD (4 blocks = heads): tbar+agg+heads+out (R6 s2_head verbatim) -----
#define CD_SMEM_BYTES (32768*4)

__global__ __launch_bounds__(256) void cd_head(
    const float* __restrict__ Wn2, const float* __restrict__ bn2,
    const float* __restrict__ Wh1, const float* __restrict__ bh1,
    const float* __restrict__ Wh2, const float* __restrict__ bh2,
    const float* __restrict__ tpart_ws,                     // (8,256)
    float* __restrict__ out)                                // (4)
{
    extern __shared__ float sm[];
    __shared__ __align__(16) float tp_s[2048];
    __shared__ __align__(16) float tbar_s[256];
    __shared__ __align__(16) float agg_s[256];
    __shared__ __align__(16) float h1h_s[128];
    __shared__ __align__(16) float wh2_s[128];

    float* bufA = sm;            // 16384 floats (64 KB)
    float* bufB = sm + 16384;    // 16384 floats

    const int tid = threadIdx.x;
    const int k   = blockIdx.x;

    stage_contig(tpart_ws, tp_s, 2048, tid);
    stage_contig(Wn2,          bufA, 16384, tid);           // rows 0..63
    stage_contig(Wn2 + 16384,  bufB, 16384, tid);           // rows 64..127
    const float bbn2  = bn2[tid];
    const float bbh1k = (tid < 128) ? bh1[k*128 + tid] : 0.f;
    if (tid < 128) wh2_s[tid] = Wh2[k*128 + tid];
    const float bbh2k = bh2[k];
    __syncthreads();                                        // A

    {   // tbar: verbatim (q ascending, then *1/64)
        float tb = 0.f;
        #pragma unroll
        for (int q = 0; q < 8; ++q) tb += tp_s[q*256 + tid];
        tbar_s[tid] = tb * (1.f/64.f);
    }
    __syncthreads();                                        // B

    // agg: verbatim chunk structure, jc ascending 0..255, thread c = tid
    float acc = bbn2;
    for (int jc = 0; jc < 64; jc += 32) {                   // bufA
        float w[32];
        #pragma unroll
        for (int u = 0; u < 32; ++u) w[u] = bufA[(jc+u)*256 + tid];
        #pragma unroll
        for (int u = 0; u < 32; u += 4) {
            const float4 t4 = *(const float4*)&tbar_s[jc + u];
            acc += t4.x*w[u] + t4.y*w[u+1] + t4.z*w[u+2] + t4.w*w[u+3];
        }
    }
    __syncthreads();                                        // C (bufA free)
    stage_contig(Wn2 + 32768, bufA, 16384, tid);            // rows 128..191
    for (int jc = 64; jc < 128; jc += 32) {                 // bufB
        float w[32];
        #pragma unroll
        for (int u = 0; u < 32; ++u) w[u] = bufB[(jc-64+u)*256 + tid];
        #pragma unroll
        for (int u = 0; u < 32; u += 4) {
            const float4 t4 = *(const float4*)&tbar_s[jc + u];
            acc += t4.x*w[u] + t4.y*w[u+1] + t4.z*w[u+2] + t4.w*w[u+3];
        }
    }
    __syncthreads();                                        // D (bufB free)
    stage_contig(Wn2 + 49152, bufB, 16384, tid);            // rows 192..255
    for (int jc = 128; jc < 192; jc += 32) {                // bufA
        float w[32];
        #pragma unroll
        for (int u = 0; u < 32; ++u) w[u] = bufA[(jc-128+u)*256 + tid];
        #pragma unroll
        for (int u = 0; u < 32; u += 4) {
            const float4 t4 = *(const float4*)&tbar_s[jc + u];
            acc += t4.x*w[u] + t4.y*w[u+1] + t4.z*w[u+2] + t4.w*w[u+3];
        }
    }
    __syncthreads();                                        // E
    for (int jc = 192; jc < 256; jc += 32) {                // bufB
        float w[32];
        #pragma unroll
        for (int u = 0; u < 32; ++u) w[u] = bufB[(jc-192+u)*256 + tid];
        #pragma unroll
        for (int u = 0; u < 32; u += 4) {
            const float4 t4 = *(const float4*)&tbar_s[jc + u];
            acc += t4.x*w[u] + t4.y*w[u+1] + t4.z*w[u+2] + t4.w*w[u+3];
        }
    }
    agg_s[tid] = acc;
    __syncthreads();                                        // F (bufs free)
    stage_contig(Wh1 + k*32768,         bufA, 16384, tid);  // Wh1[k] rows 0..127
    stage_contig(Wh1 + k*32768 + 16384, bufB, 16384, tid);  // rows 128..255
    __syncthreads();                                        // G

    if (tid < 128) {   // heads: verbatim chunk structure, cc ascending
        const int d = tid;
        float a = bbh1k;
        for (int cc = 0; cc < 128; cc += 16) {
            float wa[16];
            #pragma unroll
            for (int u = 0; u < 16; ++u) wa[u] = bufA[(cc+u)*128 + d];
            #pragma unroll
            for (int u = 0; u < 16; u += 4) {
                const float4 a4 = *(const float4*)&agg_s[cc + u];
                a += a4.x*wa[u] + a4.y*wa[u+1] + a4.z*wa[u+2] + a4.w*wa[u+3];
            }
        }
        for (int cc = 128; cc < 256; cc += 16) {
            float wa[16];
            #pragma unroll
            for (int u = 0; u < 16; ++u) wa[u] = bufB[(cc-128+u)*128 + d];
            #pragma unroll
            for (int u = 0; u < 16; u += 4) {
                const float4 a4 = *(const float4*)&agg_s[cc + u];
                a += a4.x*wa[u] + a4.y*wa[u+1] + a4.z*wa[u+2] + a4.w*wa[u+3];
            }
        }
        h1h_s[d] = fmaxf(a, 0.f);
    }
    __syncthreads();                                        // H
    if (tid == 0) {    // verbatim strictly-sequential final dot
        float a = bbh2k;
        for (int d = 0; d < 128; ++d) a += h1h_s[d] * wh2_s[d];
        out[k] = a;
    }
}

extern "C" void kernel_launch(void* const* d_in, const int* in_sizes, int n_in,
                              void* d_out, int out_size, void* d_ws, size_t ws_size,
                              hipStream_t stream) {
    const float* positions = (const float*)d_in[0];
    const float* grid      = (const float*)d_in[1];
    const float* W1  = (const float*)d_in[2];
    const float* b1  = (const float*)d_in[3];
    const float* W2  = (const float*)d_in[4];
    const float* b2  = (const float*)d_in[5];
    const float* W3  = (const float*)d_in[6];
    const float* b3  = (const float*)d_in[7];
    const float* Wn1 = (const float*)d_in[8];
    const float* bn1 = (const float*)d_in[9];
    const float* Wn2 = (const float*)d_in[10];
    const float* bn2 = (const float*)d_in[11];
    const float* Wh1 = (const float*)d_in[12];
    const float* bh1 = (const float*)d_in[13];
    const float* Wh2 = (const float*)d_in[14];
    const float* bh2 = (const float*)d_in[15];
    float* out = (float*)d_out;

    char* ws = (char*)d_ws;                 // fully rewritten every call
    float* gf_ws    = (float*)(ws + 0);         // 64*256 f = 64 KB
    float* tpart_ws = (float*)(ws + 65536);     // 8*256 f = 8 KB

    (void)hipFuncSetAttribute((const void*)a_gf,
                              hipFuncAttributeMaxDynamicSharedMemorySize,
                              A_SMEM_BYTES);
    (void)hipFuncSetAttribute((const void*)cd_head,
                              hipFuncAttributeMaxDynamicSharedMemorySize,
                              CD_SMEM_BYTES);

    hipLaunchKernelGGL(a_gf,     dim3(8),  dim3(256), A_SMEM_BYTES, stream,
                       positions, grid, W1, b1, W2, b2, W3, b3, gf_ws);
    hipLaunchKernelGGL(k2_tpart, dim3(64), dim3(256), 0, stream,
                       Wn1, bn1, gf_ws, tpart_ws);
    hipLaunchKernelGGL(cd_head,  dim3(4),  dim3(256), CD_SMEM_BYTES, stream,
                       Wn2, bn2, Wh1, bh1, Wh2, bh2, tpart_ws, out);
}